// Round 7
// baseline (242.090 us; speedup 1.0000x reference)
//
#include <hip/hip_runtime.h>
#include <math.h>

#define BB 8
#define LL 64
#define NP 63          // frame pairs per batch
#define MM 16          // sampled frames
#define HH 112
#define WW 112
#define HW (HH*WW)
#define CIN 3
#define CMID 8
#define COUT 3
#define TH 16          // stripe rows
#define TROWS 22       // TH + 6 halo
#define TSTRIDE 120    // 4 pad | 112 interior | 4 pad
#define NTH 448        // 16 rows x 28 col-groups of 4 px
#define NGRP 1848      // 3ch * 22rows * 28 float4-groups
#define NPREF 5        // ceil(1848/448)

// workspace byte offsets
#define WS_SCORES 0        // double[504*2] = 8064
#define WS_IDX    8192     // int[128]
#define WS_WT     8704     // float[1176]  score weights [cky][kx][o=8]
#define WS_WC     13440    // float[588]   combined weights [cky][kx][o pad4]
#define WS_BIAS2  15808    // float[4]
#define WS_PART   15872    // float[256*6]
#define WS_STATS  22016    // float[6]
#define WS_ZERO   22528    // float[256] zero page (prep zeroes it)

#define PD_EPS 1e-6f
#define BN_EPS 1e-5f

// ---------------------------------------------------------------- prep
__global__ void prep_kernel(const float* __restrict__ cw, const float* __restrict__ cb,
                            const float* __restrict__ bw, char* __restrict__ ws)
{
    float* wT = (float*)(ws + WS_WT);
    float* wc = (float*)(ws + WS_WC);
    float* b2 = (float*)(ws + WS_BIAS2);
    float* zp = (float*)(ws + WS_ZERO);
    int tid = threadIdx.x;
    zp[tid] = 0.f;                            // zero page (256 threads)
    for (int i = tid; i < CIN*49*CMID; i += 256) {
        int cky = i / 56, r = i % 56, kx = r / 8, o = r % 8;
        int c = cky / 7, ky = cky % 7;
        wT[i] = cw[((o*CIN + c)*7 + ky)*7 + kx];
    }
    for (int i = tid; i < CIN*49; i += 256) {
        int c = i / 49, ky = (i / 7) % 7, kx = i % 7;
        for (int o = 0; o < COUT; ++o) {
            float s = 0.f;
            for (int m = 0; m < CMID; ++m)
                s += bw[o*CMID + m] * cw[((m*CIN + c)*7 + ky)*7 + kx];
            wc[(c*7 + ky)*28 + kx*4 + o] = s;
        }
        wc[(c*7 + ky)*28 + kx*4 + 3] = 0.f;
    }
    if (tid < COUT) {
        float s = 0.f;
        for (int m = 0; m < CMID; ++m) s += bw[tid*CMID + m] * cb[m];
        b2[tid] = s;
    }
}

// decompose group g -> source offset / validity / lds index
#define GRP_ADDR(SS)                                                         \
    int g = tid + k*NTH;                                                     \
    int c = g / (TROWS*28);                                                  \
    int rem = g - c*(TROWS*28);                                              \
    int r = rem / 28;                                                        \
    int q = rem - r*28;                                                      \
    int gr = (SS)*TH - 3 + r;                                                \
    bool vld = (g < NGRP) & ((unsigned)gr < HH);                             \
    int off = c*HW + gr*WW + q*4;                                            \
    int li = (c*TROWS + r)*TSTRIDE + 4 + q*4;

// ---------------------------------------------------------------- scores
// 2 blocks per pair (stripes 0-3 / 4-6). Double-buffered LDS diff tile.
// float4 register prefetch pinned EARLY via sched_barrier(0) fences:
//   PREF(s+1) | fence | compute(s) | fence | regs->LDS | barrier
// so the vmcnt drain lands after the 9408-cycle FMA phase, not before it.
// Weights via contiguous uniform s_load -> SGPR FMA operands.
__global__ __launch_bounds__(NTH) void score_kernel(
    const float* __restrict__ x, char* __restrict__ ws)
{
    __shared__ __align__(16) float tile[2][CIN][TROWS][TSTRIDE];  // 63360 B
    __shared__ double sred[7];
    const float* wT = (const float*)(ws + WS_WT);
    const float* zp = (const float*)(ws + WS_ZERO);
    double* scores  = (double*)(ws + WS_SCORES);

    int B = blockIdx.x;                        // 1008 blocks, 1008%8==0
    int work = (B & 7) * 126 + (B >> 3);       // XCD-chunked swizzle
    int pair = work >> 1, half = work & 1;
    int b = pair / NP, t = pair % NP;
    const float* x0 = x + (size_t)(b*LL + t) * (CIN*HW);
    const float* x1 = x0 + CIN*HW;

    int tid = threadIdx.x;
    int iy = tid / 28;
    int xb = (tid % 28) * 4;
    int s0 = half * 4, s1 = half ? 7 : 4;

    // zero the column pads of both buffers once (never rewritten)
    {
        float* tf = &tile[0][0][0][0];
        for (int i = tid; i < 2*CIN*TROWS*8; i += NTH) {
            int buf_cr = i >> 3, p8 = i & 7;
            int cc = (p8 < 4) ? p8 : 112 + p8;
            tf[buf_cr*TSTRIDE + cc] = 0.f;
        }
    }

    float4 va[NPREF], vb[NPREF];
    int    lidx[NPREF];

    // prologue stage of stripe s0
    #pragma unroll
    for (int k = 0; k < NPREF; ++k) {
        GRP_ADDR(s0);
        const float* pa = vld ? (x0 + off) : zp;
        const float* pb = vld ? (x1 + off) : zp;
        va[k] = *(const float4*)pa;
        vb[k] = *(const float4*)pb;
        lidx[k] = li;
    }
    {
        float* dst = &tile[s0 & 1][0][0][0];
        #pragma unroll
        for (int k = 0; k < NPREF; ++k) {
            if (tid + k*NTH < NGRP) {
                float4 d;
                d.x = va[k].x - vb[k].x; d.y = va[k].y - vb[k].y;
                d.z = va[k].z - vb[k].z; d.w = va[k].w - vb[k].w;
                *(float4*)&dst[lidx[k]] = d;
            }
        }
    }
    __syncthreads();

    double dacc = 0.0;

    for (int s = s0; s < s1; ++s) {
        int bu = s & 1;
        if (s + 1 < s1) {                      // issue loads EARLY
            #pragma unroll
            for (int k = 0; k < NPREF; ++k) {
                GRP_ADDR(s + 1);
                const float* pa = vld ? (x0 + off) : zp;
                const float* pb = vld ? (x1 + off) : zp;
                va[k] = *(const float4*)pa;
                vb[k] = *(const float4*)pb;
                lidx[k] = li;
            }
        }
        __builtin_amdgcn_sched_barrier(0);     // loads stay ABOVE compute

        float acc[4][8];
        #pragma unroll
        for (int p = 0; p < 4; ++p)
            #pragma unroll
            for (int o = 0; o < 8; ++o) acc[p][o] = 0.f;

        #pragma unroll 1
        for (int cky = 0; cky < 21; ++cky) {
            int c = cky / 7, ky = cky % 7;
            const float* tr = &tile[bu][c][iy + ky][xb];
            float v[12];
            *(float4*)&v[0] = *(const float4*)&tr[0];
            *(float4*)&v[4] = *(const float4*)&tr[4];
            *(float4*)&v[8] = *(const float4*)&tr[8];
            const float* wrow = wT + cky*56;          // uniform, contiguous
            #pragma unroll
            for (int kx = 0; kx < 7; ++kx) {
                #pragma unroll
                for (int o = 0; o < 8; ++o) {
                    float wv = wrow[kx*8 + o];        // s_load -> SGPR
                    #pragma unroll
                    for (int p = 0; p < 4; ++p)
                        acc[p][o] += wv * v[p + kx + 1];
                }
            }
        }

        #pragma unroll
        for (int p = 0; p < 4; ++p) {
            float ss = 0.f;
            #pragma unroll
            for (int o = 0; o < 8; ++o) {
                float d = acc[p][o] + PD_EPS;
                ss += d*d;
            }
            dacc += (double)sqrtf(ss);
        }

        __builtin_amdgcn_sched_barrier(0);     // writes stay BELOW compute
        if (s + 1 < s1) {                      // write-late (vmcnt drained here)
            float* dst = &tile[bu ^ 1][0][0][0];
            #pragma unroll
            for (int k = 0; k < NPREF; ++k) {
                if (tid + k*NTH < NGRP) {
                    float4 d;
                    d.x = va[k].x - vb[k].x; d.y = va[k].y - vb[k].y;
                    d.z = va[k].z - vb[k].z; d.w = va[k].w - vb[k].w;
                    *(float4*)&dst[lidx[k]] = d;
                }
            }
        }
        __syncthreads();
    }

    #pragma unroll
    for (int off = 32; off > 0; off >>= 1)
        dacc += __shfl_down(dacc, off, 64);
    int wid = tid >> 6, lane = tid & 63;
    if (lane == 0) sred[wid] = dacc;
    __syncthreads();
    if (tid == 0) {
        double ssum = 0.0;
        for (int w = 0; w < 7; ++w) ssum += sred[w];
        scores[pair*2 + half] = ssum;
    }
}

// ---------------------------------------------------------------- sampling
__global__ void sample_kernel(char* __restrict__ ws)
{
    __shared__ double cum[BB][NP];
    const double* scores = (const double*)(ws + WS_SCORES);
    int* idxs = (int*)(ws + WS_IDX);
    int tid = threadIdx.x;                // 128
    if (tid < BB) {
        double tot = 0.0;
        for (int t = 0; t < NP; ++t)
            tot += sqrt(scores[(tid*NP + t)*2] + scores[(tid*NP + t)*2 + 1]);
        double run = 0.0;
        for (int t = 0; t < NP; ++t) {
            run += sqrt(scores[(tid*NP + t)*2] + scores[(tid*NP + t)*2 + 1]) / tot;
            cum[tid][t] = run;
        }
    }
    __syncthreads();
    {
        int b = tid / MM, m = tid % MM;
        double target = (double)((float)m / 15.f);
        int best = 0;
        double bv = fabs(cum[b][0] - target);
        for (int t = 1; t < NP; ++t) {
            double v = fabs(cum[b][t] - target);
            if (v < bv) { bv = v; best = t; }   // strict: first min wins
        }
        idxs[tid] = best;
    }
}

// ---------------------------------------------------------------- resblock conv
// same pinned float4 pipeline; combined 7x7 3->3; y -> d_out + BN partials
__global__ __launch_bounds__(NTH) void resconv_kernel(
    const float* __restrict__ x, char* __restrict__ ws, float* __restrict__ out)
{
    __shared__ __align__(16) float tile[2][CIN][TROWS][TSTRIDE];
    __shared__ double sred[7][6];

    const float* wc    = (const float*)(ws + WS_WC);
    const float* bias2 = (const float*)(ws + WS_BIAS2);
    const float* zp    = (const float*)(ws + WS_ZERO);
    const int* idxs    = (const int*)(ws + WS_IDX);
    float* part        = (float*)(ws + WS_PART);

    int B = blockIdx.x;                        // 256 blocks
    int work = (B & 7) * 32 + (B >> 3);
    int n = work >> 1, half = work & 1;
    int b = n / MM;
    int l = idxs[n];
    const float* src = x + (size_t)(b*LL + l) * (CIN*HW);
    float* ybase = out + (size_t)n * (COUT*HW);

    int tid = threadIdx.x;
    int iy = tid / 28;
    int xb = (tid % 28) * 4;
    int s0 = half * 4, s1 = half ? 7 : 4;

    {
        float* tf = &tile[0][0][0][0];
        for (int i = tid; i < 2*CIN*TROWS*8; i += NTH) {
            int buf_cr = i >> 3, p8 = i & 7;
            int cc = (p8 < 4) ? p8 : 112 + p8;
            tf[buf_cr*TSTRIDE + cc] = 0.f;
        }
    }

    float bb0 = bias2[0], bb1 = bias2[1], bb2 = bias2[2];
    double sm0=0, sm1=0, sm2=0, sq0=0, sq1=0, sq2=0;

    float4 va[NPREF];
    int    lidx[NPREF];

    #pragma unroll
    for (int k = 0; k < NPREF; ++k) {
        GRP_ADDR(s0);
        const float* pa = vld ? (src + off) : zp;
        va[k] = *(const float4*)pa;
        lidx[k] = li;
    }
    {
        float* dst = &tile[s0 & 1][0][0][0];
        #pragma unroll
        for (int k = 0; k < NPREF; ++k)
            if (tid + k*NTH < NGRP) *(float4*)&dst[lidx[k]] = va[k];
    }
    __syncthreads();

    for (int s = s0; s < s1; ++s) {
        int bu = s & 1;
        if (s + 1 < s1) {
            #pragma unroll
            for (int k = 0; k < NPREF; ++k) {
                GRP_ADDR(s + 1);
                const float* pa = vld ? (src + off) : zp;
                va[k] = *(const float4*)pa;
                lidx[k] = li;
            }
        }
        __builtin_amdgcn_sched_barrier(0);

        float acc[4][3];
        #pragma unroll
        for (int p = 0; p < 4; ++p) { acc[p][0]=0.f; acc[p][1]=0.f; acc[p][2]=0.f; }

        #pragma unroll 1
        for (int cky = 0; cky < 21; ++cky) {
            int c = cky / 7, ky = cky % 7;
            const float* tr = &tile[bu][c][iy + ky][xb];
            float v[12];
            *(float4*)&v[0] = *(const float4*)&tr[0];
            *(float4*)&v[4] = *(const float4*)&tr[4];
            *(float4*)&v[8] = *(const float4*)&tr[8];
            const float* wrow = wc + cky*28;          // uniform, contiguous
            #pragma unroll
            for (int kx = 0; kx < 7; ++kx) {
                #pragma unroll
                for (int o = 0; o < 3; ++o) {
                    float wv = wrow[kx*4 + o];        // s_load -> SGPR
                    #pragma unroll
                    for (int p = 0; p < 4; ++p)
                        acc[p][o] += wv * v[p + kx + 1];
                }
            }
        }

        int gy = s*TH + iy;
        float4 yv; float* pyv = (float*)&yv;
        #pragma unroll
        for (int p = 0; p < 4; ++p) {
            float val = acc[p][0] + bb0;
            pyv[p] = val; sm0 += val; sq0 += (double)val*val;
        }
        *(float4*)&ybase[0*HW + gy*WW + xb] = yv;
        #pragma unroll
        for (int p = 0; p < 4; ++p) {
            float val = acc[p][1] + bb1;
            pyv[p] = val; sm1 += val; sq1 += (double)val*val;
        }
        *(float4*)&ybase[1*HW + gy*WW + xb] = yv;
        #pragma unroll
        for (int p = 0; p < 4; ++p) {
            float val = acc[p][2] + bb2;
            pyv[p] = val; sm2 += val; sq2 += (double)val*val;
        }
        *(float4*)&ybase[2*HW + gy*WW + xb] = yv;

        __builtin_amdgcn_sched_barrier(0);
        if (s + 1 < s1) {
            float* dst = &tile[bu ^ 1][0][0][0];
            #pragma unroll
            for (int k = 0; k < NPREF; ++k)
                if (tid + k*NTH < NGRP) *(float4*)&dst[lidx[k]] = va[k];
        }
        __syncthreads();
    }

    double vals[6] = {sm0, sm1, sm2, sq0, sq1, sq2};
    #pragma unroll
    for (int j = 0; j < 6; ++j) {
        #pragma unroll
        for (int off = 32; off > 0; off >>= 1)
            vals[j] += __shfl_down(vals[j], off, 64);
    }
    int wid = tid >> 6, lane = tid & 63;
    if (lane == 0) {
        #pragma unroll
        for (int j = 0; j < 6; ++j) sred[wid][j] = vals[j];
    }
    __syncthreads();
    if (tid < 6) {
        double s = 0.0;
        for (int w = 0; w < 7; ++w) s += sred[w][tid];
        part[B*6 + tid] = (float)s;
    }
}

// ---------------------------------------------------------------- stats reduce
__global__ void statreduce_kernel(char* __restrict__ ws)
{
    const float* part = (const float*)(ws + WS_PART);
    float* stats = (float*)(ws + WS_STATS);
    int tid = threadIdx.x;            // 384: 6 cols x 64 lanes
    int j = tid >> 6, lane = tid & 63;
    double s = 0.0;
    for (int n = lane; n < 256; n += 64) s += (double)part[n*6 + j];
    #pragma unroll
    for (int off = 32; off > 0; off >>= 1)
        s += __shfl_down(s, off, 64);
    if (lane == 0) stats[j] = (float)s;
}

// ---------------------------------------------------------------- finalize
__global__ __launch_bounds__(256) void finalize_kernel(
    const float* __restrict__ x, const float* __restrict__ gamma,
    const float* __restrict__ beta, const char* __restrict__ ws,
    float* __restrict__ out)
{
    const float* stats = (const float*)(ws + WS_STATS);
    const int* idxs    = (const int*)(ws + WS_IDX);
    int i4 = blockIdx.x * 256 + threadIdx.x;
    int i  = i4 * 4;
    int n  = i / (COUT*HW);
    int c  = (i / HW) % COUT;
    int hw = i % HW;
    int b  = n / MM;
    int l  = idxs[n];
    const float Ninv = 1.f / (float)(BB*MM*HW);
    float mean  = stats[c] * Ninv;
    float var   = stats[3+c] * Ninv - mean*mean;
    float scale = gamma[c] / sqrtf(var + BN_EPS);
    float shift = beta[c] - mean*scale;
    float4 y  = *(const float4*)&out[i];
    float4 xv = *(const float4*)&x[((size_t)(b*LL + l)*CIN + c)*HW + hw];
    float4 r;
    r.x = xv.x + fmaxf(y.x*scale + shift, 0.f);
    r.y = xv.y + fmaxf(y.y*scale + shift, 0.f);
    r.z = xv.z + fmaxf(y.z*scale + shift, 0.f);
    r.w = xv.w + fmaxf(y.w*scale + shift, 0.f);
    *(float4*)&out[i] = r;
}

// ---------------------------------------------------------------- launch
extern "C" void kernel_launch(void* const* d_in, const int* in_sizes, int n_in,
                              void* d_out, int out_size, void* d_ws, size_t ws_size,
                              hipStream_t stream)
{
    const float* x       = (const float*)d_in[0];
    const float* conv_w  = (const float*)d_in[1];
    const float* conv_b  = (const float*)d_in[2];
    const float* bneck_w = (const float*)d_in[3];
    const float* gamma   = (const float*)d_in[4];
    const float* beta    = (const float*)d_in[5];
    float* out = (float*)d_out;
    char* ws   = (char*)d_ws;

    prep_kernel<<<1, 256, 0, stream>>>(conv_w, conv_b, bneck_w, ws);
    score_kernel<<<BB*NP*2, NTH, 0, stream>>>(x, ws);
    sample_kernel<<<1, 128, 0, stream>>>(ws);
    resconv_kernel<<<BB*MM*2, NTH, 0, stream>>>(x, ws, out);
    statreduce_kernel<<<1, 384, 0, stream>>>(ws);
    int total4 = (BB*MM*COUT*HW) / 4;
    finalize_kernel<<<total4 / 256, 256, 0, stream>>>(x, gamma, beta, ws, out);
}

// Round 8
// 229.393 us; speedup vs baseline: 1.0554x; 1.0554x over previous
//
#include <hip/hip_runtime.h>
#include <math.h>

#define BB 8
#define LL 64
#define NP 63          // frame pairs per batch
#define MM 16          // sampled frames
#define HH 112
#define WW 112
#define HW (HH*WW)
#define CIN 3
#define CMID 8
#define COUT 3
#define NTH 448        // 112 rows x 4 col-groups of 4 px
#define TROWS 118      // 112 + 6 row halo
#define TCOLS 24       // 4 pad | 16 interior | 4 (incl right pad/halo)
#define NCHUNK 2124    // 3 * 118 * 6 float4-chunks
#define CPC 708        // chunks per channel (118*6)
#define NSTR 7         // column strips per frame

// workspace byte offsets
#define WS_SCORES 0        // double[504*7] = 28224
#define WS_IDX    28672    // int[128]
#define WS_WT     29184    // float[1176]  score weights [cky][kx][o=8]
#define WS_WC     34048    // float[588]   combined weights [cky][kx][o pad4]
#define WS_BIAS2  36480    // float[4]
#define WS_PART   36608    // float[896*6] = 21504
#define WS_STATS  58112    // float[6]
#define WS_ZERO   58368    // float[256] zero page

#define PD_EPS 1e-6f
#define BN_EPS 1e-5f

// ---------------------------------------------------------------- prep
__global__ void prep_kernel(const float* __restrict__ cw, const float* __restrict__ cb,
                            const float* __restrict__ bw, char* __restrict__ ws)
{
    float* wT = (float*)(ws + WS_WT);
    float* wc = (float*)(ws + WS_WC);
    float* b2 = (float*)(ws + WS_BIAS2);
    float* zp = (float*)(ws + WS_ZERO);
    int tid = threadIdx.x;
    zp[tid] = 0.f;
    for (int i = tid; i < CIN*49*CMID; i += 256) {
        int cky = i / 56, r = i % 56, kx = r / 8, o = r % 8;
        int c = cky / 7, ky = cky % 7;
        wT[i] = cw[((o*CIN + c)*7 + ky)*7 + kx];
    }
    for (int i = tid; i < CIN*49; i += 256) {
        int c = i / 49, ky = (i / 7) % 7, kx = i % 7;
        for (int o = 0; o < COUT; ++o) {
            float s = 0.f;
            for (int m = 0; m < CMID; ++m)
                s += bw[o*CMID + m] * cw[((m*CIN + c)*7 + ky)*7 + kx];
            wc[(c*7 + ky)*28 + kx*4 + o] = s;
        }
        wc[(c*7 + ky)*28 + kx*4 + 3] = 0.f;
    }
    if (tid < COUT) {
        float s = 0.f;
        for (int m = 0; m < CMID; ++m) s += bw[tid*CMID + m] * cb[m];
        b2[tid] = s;
    }
}

// chunk idx -> tile/global coords. tile row t <-> global row t-3.
#define CHUNK_ADDR                                                           \
    int idx = tid + k*NTH;                                                   \
    int c   = idx / CPC;                                                     \
    int rem = idx - c*CPC;                                                   \
    int row = rem / 6;                                                       \
    int q   = rem - row*6;                                                   \
    int gr  = row - 3;                                                       \
    int gc  = x0col + q*4;                                                   \
    bool vld = (idx < NCHUNK) & ((unsigned)gr < HH) & ((unsigned)gc <= 108); \
    int off = c*HW + gr*WW + gc;                                             \
    int li  = c*(TROWS*TCOLS) + row*TCOLS + q*4;

// ---------------------------------------------------------------- scores
// block = one pair x one 16-col full-height strip. Single LDS stage of the
// diff image, ONE barrier, then barrier-free FMA phase. Occupancy does the
// latency hiding: 33.2KB LDS -> 4 blocks/CU -> 28 waves/CU.
// Weights via contiguous uniform s_load -> SGPR FMA operands.
__global__ __launch_bounds__(NTH) void score_kernel(
    const float* __restrict__ x, char* __restrict__ ws)
{
    __shared__ __align__(16) float tile[CIN][TROWS][TCOLS];   // 33984 B
    __shared__ double sred[7];
    const float* wT = (const float*)(ws + WS_WT);
    const float* zp = (const float*)(ws + WS_ZERO);
    double* scores  = (double*)(ws + WS_SCORES);

    int B = blockIdx.x;                        // 3528 blocks, 3528%8==0
    int work = (B & 7) * 441 + (B >> 3);       // XCD-chunked swizzle
    int pair = work / NSTR, strip = work - pair*NSTR;
    int b = pair / NP, t = pair - b*NP;
    const float* x0 = x + (size_t)(b*LL + t) * (CIN*HW);
    const float* x1 = x0 + CIN*HW;
    int x0col = strip*16 - 4;

    int tid = threadIdx.x;
    int r  = tid >> 2;          // output row 0..111
    int cg = tid & 3;           // col group: cols strip*16 + cg*4 .. +3

    // single stage: diff image -> LDS (sequential chunks, conflict-free writes)
    float* tf = &tile[0][0][0];
    #pragma unroll
    for (int k = 0; k < 5; ++k) {
        CHUNK_ADDR;
        const float* pa = vld ? (x0 + off) : zp;
        const float* pb = vld ? (x1 + off) : zp;
        float4 va = *(const float4*)pa;
        float4 vb = *(const float4*)pb;
        float4 d;
        d.x = va.x - vb.x; d.y = va.y - vb.y;
        d.z = va.z - vb.z; d.w = va.w - vb.w;
        if (idx < NCHUNK) *(float4*)&tf[li] = d;
    }
    __syncthreads();

    float acc[4][8];
    #pragma unroll
    for (int p = 0; p < 4; ++p)
        #pragma unroll
        for (int o = 0; o < 8; ++o) acc[p][o] = 0.f;

    #pragma unroll 1
    for (int cky = 0; cky < 21; ++cky) {
        int c = cky / 7, ky = cky % 7;
        const float* tr = &tile[c][r + ky][cg*4];
        float v[12];
        *(float4*)&v[0] = *(const float4*)&tr[0];
        *(float4*)&v[4] = *(const float4*)&tr[4];
        *(float4*)&v[8] = *(const float4*)&tr[8];
        const float* wrow = wT + cky*56;              // uniform -> s_load
        #pragma unroll
        for (int kx = 0; kx < 7; ++kx) {
            #pragma unroll
            for (int o = 0; o < 8; ++o) {
                float wv = wrow[kx*8 + o];            // SGPR operand
                #pragma unroll
                for (int p = 0; p < 4; ++p)
                    acc[p][o] += wv * v[p + kx + 1];
            }
        }
    }

    double dacc = 0.0;
    #pragma unroll
    for (int p = 0; p < 4; ++p) {
        float ss = 0.f;
        #pragma unroll
        for (int o = 0; o < 8; ++o) {
            float d = acc[p][o] + PD_EPS;
            ss += d*d;
        }
        dacc += (double)sqrtf(ss);
    }

    #pragma unroll
    for (int off2 = 32; off2 > 0; off2 >>= 1)
        dacc += __shfl_down(dacc, off2, 64);
    int wid = tid >> 6, lane = tid & 63;
    if (lane == 0) sred[wid] = dacc;
    __syncthreads();
    if (tid == 0) {
        double ssum = 0.0;
        for (int w = 0; w < 7; ++w) ssum += sred[w];
        scores[pair*NSTR + strip] = ssum;
    }
}

// ---------------------------------------------------------------- sampling
__global__ void sample_kernel(char* __restrict__ ws)
{
    __shared__ double cum[BB][NP];
    const double* scores = (const double*)(ws + WS_SCORES);
    int* idxs = (int*)(ws + WS_IDX);
    int tid = threadIdx.x;                // 128
    if (tid < BB) {
        double tot = 0.0;
        for (int t = 0; t < NP; ++t) {
            const double* sp = scores + (tid*NP + t)*NSTR;
            double s = 0.0;
            for (int u = 0; u < NSTR; ++u) s += sp[u];
            tot += sqrt(s);
        }
        double run = 0.0;
        for (int t = 0; t < NP; ++t) {
            const double* sp = scores + (tid*NP + t)*NSTR;
            double s = 0.0;
            for (int u = 0; u < NSTR; ++u) s += sp[u];
            run += sqrt(s) / tot;
            cum[tid][t] = run;
        }
    }
    __syncthreads();
    {
        int b = tid / MM, m = tid % MM;
        double target = (double)((float)m / 15.f);
        int best = 0;
        double bv = fabs(cum[b][0] - target);
        for (int t = 1; t < NP; ++t) {
            double v = fabs(cum[b][t] - target);
            if (v < bv) { bv = v; best = t; }   // strict: first min wins
        }
        idxs[tid] = best;
    }
}

// ---------------------------------------------------------------- resblock conv
// block = one selected frame x one strip; same single-stage structure.
// combined 7x7 3->3; y -> d_out + BN partials.
__global__ __launch_bounds__(NTH) void resconv_kernel(
    const float* __restrict__ x, char* __restrict__ ws, float* __restrict__ out)
{
    __shared__ __align__(16) float tile[CIN][TROWS][TCOLS];
    __shared__ double sred[7][6];

    const float* wc    = (const float*)(ws + WS_WC);
    const float* bias2 = (const float*)(ws + WS_BIAS2);
    const float* zp    = (const float*)(ws + WS_ZERO);
    const int* idxs    = (const int*)(ws + WS_IDX);
    float* part        = (float*)(ws + WS_PART);

    int B = blockIdx.x;                        // 896 blocks, 896%8==0
    int work = (B & 7) * 112 + (B >> 3);
    int n = work / NSTR, strip = work - n*NSTR;
    int b = n / MM;
    int l = idxs[n];
    const float* src = x + (size_t)(b*LL + l) * (CIN*HW);
    float* ybase = out + (size_t)n * (COUT*HW);
    int x0col = strip*16 - 4;

    int tid = threadIdx.x;
    int r  = tid >> 2;
    int cg = tid & 3;

    float* tf = &tile[0][0][0];
    #pragma unroll
    for (int k = 0; k < 5; ++k) {
        CHUNK_ADDR;
        const float* pa = vld ? (src + off) : zp;
        float4 va = *(const float4*)pa;
        if (idx < NCHUNK) *(float4*)&tf[li] = va;
    }
    __syncthreads();

    float acc[4][3];
    #pragma unroll
    for (int p = 0; p < 4; ++p) { acc[p][0]=0.f; acc[p][1]=0.f; acc[p][2]=0.f; }

    #pragma unroll 1
    for (int cky = 0; cky < 21; ++cky) {
        int c = cky / 7, ky = cky % 7;
        const float* tr = &tile[c][r + ky][cg*4];
        float v[12];
        *(float4*)&v[0] = *(const float4*)&tr[0];
        *(float4*)&v[4] = *(const float4*)&tr[4];
        *(float4*)&v[8] = *(const float4*)&tr[8];
        const float* wrow = wc + cky*28;              // uniform -> s_load
        #pragma unroll
        for (int kx = 0; kx < 7; ++kx) {
            #pragma unroll
            for (int o = 0; o < 3; ++o) {
                float wv = wrow[kx*4 + o];            // SGPR operand
                #pragma unroll
                for (int p = 0; p < 4; ++p)
                    acc[p][o] += wv * v[p + kx + 1];
            }
        }
    }

    double sm0=0, sm1=0, sm2=0, sq0=0, sq1=0, sq2=0;
    float bb0 = bias2[0], bb1 = bias2[1], bb2 = bias2[2];
    int ocol = strip*16 + cg*4;
    float4 yv; float* pyv = (float*)&yv;
    #pragma unroll
    for (int p = 0; p < 4; ++p) {
        float val = acc[p][0] + bb0;
        pyv[p] = val; sm0 += val; sq0 += (double)val*val;
    }
    *(float4*)&ybase[0*HW + r*WW + ocol] = yv;
    #pragma unroll
    for (int p = 0; p < 4; ++p) {
        float val = acc[p][1] + bb1;
        pyv[p] = val; sm1 += val; sq1 += (double)val*val;
    }
    *(float4*)&ybase[1*HW + r*WW + ocol] = yv;
    #pragma unroll
    for (int p = 0; p < 4; ++p) {
        float val = acc[p][2] + bb2;
        pyv[p] = val; sm2 += val; sq2 += (double)val*val;
    }
    *(float4*)&ybase[2*HW + r*WW + ocol] = yv;

    double vals[6] = {sm0, sm1, sm2, sq0, sq1, sq2};
    #pragma unroll
    for (int j = 0; j < 6; ++j) {
        #pragma unroll
        for (int off2 = 32; off2 > 0; off2 >>= 1)
            vals[j] += __shfl_down(vals[j], off2, 64);
    }
    int wid = tid >> 6, lane = tid & 63;
    if (lane == 0) {
        #pragma unroll
        for (int j = 0; j < 6; ++j) sred[wid][j] = vals[j];
    }
    __syncthreads();
    if (tid < 6) {
        double s = 0.0;
        for (int w = 0; w < 7; ++w) s += sred[w][tid];
        part[B*6 + tid] = (float)s;
    }
}

// ---------------------------------------------------------------- stats reduce
__global__ void statreduce_kernel(char* __restrict__ ws)
{
    const float* part = (const float*)(ws + WS_PART);
    float* stats = (float*)(ws + WS_STATS);
    int tid = threadIdx.x;            // 384: 6 cols x 64 lanes
    int j = tid >> 6, lane = tid & 63;
    double s = 0.0;
    for (int n = lane; n < 896; n += 64) s += (double)part[n*6 + j];
    #pragma unroll
    for (int off = 32; off > 0; off >>= 1)
        s += __shfl_down(s, off, 64);
    if (lane == 0) stats[j] = (float)s;
}

// ---------------------------------------------------------------- finalize
__global__ __launch_bounds__(256) void finalize_kernel(
    const float* __restrict__ x, const float* __restrict__ gamma,
    const float* __restrict__ beta, const char* __restrict__ ws,
    float* __restrict__ out)
{
    const float* stats = (const float*)(ws + WS_STATS);
    const int* idxs    = (const int*)(ws + WS_IDX);
    int i4 = blockIdx.x * 256 + threadIdx.x;
    int i  = i4 * 4;
    int n  = i / (COUT*HW);
    int c  = (i / HW) % COUT;
    int hw = i % HW;
    int b  = n / MM;
    int l  = idxs[n];
    const float Ninv = 1.f / (float)(BB*MM*HW);
    float mean  = stats[c] * Ninv;
    float var   = stats[3+c] * Ninv - mean*mean;
    float scale = gamma[c] / sqrtf(var + BN_EPS);
    float shift = beta[c] - mean*scale;
    float4 y  = *(const float4*)&out[i];
    float4 xv = *(const float4*)&x[((size_t)(b*LL + l)*CIN + c)*HW + hw];
    float4 r;
    r.x = xv.x + fmaxf(y.x*scale + shift, 0.f);
    r.y = xv.y + fmaxf(y.y*scale + shift, 0.f);
    r.z = xv.z + fmaxf(y.z*scale + shift, 0.f);
    r.w = xv.w + fmaxf(y.w*scale + shift, 0.f);
    *(float4*)&out[i] = r;
}

// ---------------------------------------------------------------- launch
extern "C" void kernel_launch(void* const* d_in, const int* in_sizes, int n_in,
                              void* d_out, int out_size, void* d_ws, size_t ws_size,
                              hipStream_t stream)
{
    const float* x       = (const float*)d_in[0];
    const float* conv_w  = (const float*)d_in[1];
    const float* conv_b  = (const float*)d_in[2];
    const float* bneck_w = (const float*)d_in[3];
    const float* gamma   = (const float*)d_in[4];
    const float* beta    = (const float*)d_in[5];
    float* out = (float*)d_out;
    char* ws   = (char*)d_ws;

    prep_kernel<<<1, 256, 0, stream>>>(conv_w, conv_b, bneck_w, ws);
    score_kernel<<<BB*NP*NSTR, NTH, 0, stream>>>(x, ws);
    sample_kernel<<<1, 128, 0, stream>>>(ws);
    resconv_kernel<<<BB*MM*NSTR, NTH, 0, stream>>>(x, ws, out);
    statreduce_kernel<<<1, 384, 0, stream>>>(ws);
    int total4 = (BB*MM*COUT*HW) / 4;
    finalize_kernel<<<total4 / 256, 256, 0, stream>>>(x, gamma, beta, ws, out);
}

// Round 9
// 222.089 us; speedup vs baseline: 1.0901x; 1.0329x over previous
//
#include <hip/hip_runtime.h>
#include <math.h>

#define BB 8
#define LL 64
#define NP 63          // frame pairs per batch
#define MM 16          // sampled frames
#define HH 112
#define WW 112
#define HW (HH*WW)
#define CIN 3
#define CMID 8
#define COUT 3
#define NTH 448        // 112 rows x 4 col-groups of 4 px
#define TROWS 118      // 112 + 6 row halo
#define TCOLS 24       // 4 pad | 16 interior | 4 (incl right pad/halo)
#define NCHUNK 2124    // 3 * 118 * 6 float4-chunks
#define CPC 708        // chunks per channel (118*6)
#define NSTR 7         // column strips per frame

// workspace byte offsets
#define WS_SCORES 0        // double[504*7] = 28224
#define WS_IDX    28672    // int[128]
#define WS_WT     29184    // float[1176]  score weights [cky][kx][o=8]
#define WS_WC     34048    // float[588]   combined weights [cky][kx][o pad4]
#define WS_BIAS2  36480    // float[4]
#define WS_PART   36608    // float[896*6] = 21504
#define WS_STATS  58112    // float[6]
#define WS_ZERO   58368    // float[256] zero page

#define PD_EPS 1e-6f
#define BN_EPS 1e-5f

// ---------------------------------------------------------------- prep
__global__ void prep_kernel(const float* __restrict__ cw, const float* __restrict__ cb,
                            const float* __restrict__ bw, char* __restrict__ ws)
{
    float* wT = (float*)(ws + WS_WT);
    float* wc = (float*)(ws + WS_WC);
    float* b2 = (float*)(ws + WS_BIAS2);
    float* zp = (float*)(ws + WS_ZERO);
    int tid = threadIdx.x;
    zp[tid] = 0.f;
    for (int i = tid; i < CIN*49*CMID; i += 256) {
        int cky = i / 56, r = i % 56, kx = r / 8, o = r % 8;
        int c = cky / 7, ky = cky % 7;
        wT[i] = cw[((o*CIN + c)*7 + ky)*7 + kx];
    }
    for (int i = tid; i < CIN*49; i += 256) {
        int c = i / 49, ky = (i / 7) % 7, kx = i % 7;
        for (int o = 0; o < COUT; ++o) {
            float s = 0.f;
            for (int m = 0; m < CMID; ++m)
                s += bw[o*CMID + m] * cw[((m*CIN + c)*7 + ky)*7 + kx];
            wc[(c*7 + ky)*28 + kx*4 + o] = s;
        }
        wc[(c*7 + ky)*28 + kx*4 + 3] = 0.f;
    }
    if (tid < COUT) {
        float s = 0.f;
        for (int m = 0; m < CMID; ++m) s += bw[tid*CMID + m] * cb[m];
        b2[tid] = s;
    }
}

// chunk idx -> tile/global coords. tile row t <-> global row t-3.
#define CHUNK_ADDR                                                           \
    int idx = tid + k*NTH;                                                   \
    int c   = idx / CPC;                                                     \
    int rem = idx - c*CPC;                                                   \
    int row = rem / 6;                                                       \
    int q   = rem - row*6;                                                   \
    int gr  = row - 3;                                                       \
    int gc  = x0col + q*4;                                                   \
    bool vld = (idx < NCHUNK) & ((unsigned)gr < HH) & ((unsigned)gc <= 108); \
    int off = c*HW + gr*WW + gc;                                             \
    int li  = c*(TROWS*TCOLS) + row*TCOLS + q*4;

// ---------------------------------------------------------------- scores
// block = one pair x one 16-col full-height strip. Single LDS stage of the
// diff image, ONE barrier, barrier-free FMA phase; 4 blocks/CU = 28 waves.
// Inner loop: ky fully unrolled with ONE-KY-AHEAD register preload of the
// tile window, so each ky's FMAs depend on ds_reads issued one iteration
// earlier (already landed) — the lgkmcnt drain before the FMA block no
// longer exposes the ~120cy ds_read latency (only the fast s_load weights).
__global__ __launch_bounds__(NTH) void score_kernel(
    const float* __restrict__ x, char* __restrict__ ws)
{
    __shared__ __align__(16) float tile[CIN][TROWS][TCOLS];   // 33984 B
    __shared__ double sred[7];
    const float* wT = (const float*)(ws + WS_WT);
    const float* zp = (const float*)(ws + WS_ZERO);
    double* scores  = (double*)(ws + WS_SCORES);

    int B = blockIdx.x;                        // 3528 blocks, 3528%8==0
    int work = (B & 7) * 441 + (B >> 3);       // XCD-chunked swizzle
    int pair = work / NSTR, strip = work - pair*NSTR;
    int b = pair / NP, t = pair - b*NP;
    const float* x0 = x + (size_t)(b*LL + t) * (CIN*HW);
    const float* x1 = x0 + CIN*HW;
    int x0col = strip*16 - 4;

    int tid = threadIdx.x;
    int r  = tid >> 2;          // output row 0..111
    int cg = tid & 3;           // col group: cols strip*16 + cg*4 .. +3

    // single stage: diff image -> LDS
    float* tf = &tile[0][0][0];
    #pragma unroll
    for (int k = 0; k < 5; ++k) {
        CHUNK_ADDR;
        const float* pa = vld ? (x0 + off) : zp;
        const float* pb = vld ? (x1 + off) : zp;
        float4 va = *(const float4*)pa;
        float4 vb = *(const float4*)pb;
        float4 d;
        d.x = va.x - vb.x; d.y = va.y - vb.y;
        d.z = va.z - vb.z; d.w = va.w - vb.w;
        if (idx < NCHUNK) *(float4*)&tf[li] = d;
    }
    __syncthreads();

    float acc[4][8];
    #pragma unroll
    for (int p = 0; p < 4; ++p)
        #pragma unroll
        for (int o = 0; o < 8; ++o) acc[p][o] = 0.f;

    #pragma unroll 1
    for (int c = 0; c < CIN; ++c) {
        const float* tc = &tile[c][r][cg*4];      // ky=0 row base
        float4 n0 = *(const float4*)&tc[0];       // preload ky=0 window
        float4 n1 = *(const float4*)&tc[4];
        float4 n2 = *(const float4*)&tc[8];
        #pragma unroll
        for (int ky = 0; ky < 7; ++ky) {
            float v[12];
            *(float4*)&v[0] = n0;
            *(float4*)&v[4] = n1;
            *(float4*)&v[8] = n2;
            if (ky < 6) {                          // issue NEXT ky's reads now
                const float* tn = tc + (ky + 1)*TCOLS;
                n0 = *(const float4*)&tn[0];
                n1 = *(const float4*)&tn[4];
                n2 = *(const float4*)&tn[8];
            }
            const float* wrow = wT + (c*7 + ky)*56;   // uniform -> s_load
            #pragma unroll
            for (int kx = 0; kx < 7; ++kx) {
                #pragma unroll
                for (int o = 0; o < 8; ++o) {
                    float wv = wrow[kx*8 + o];        // SGPR operand
                    #pragma unroll
                    for (int p = 0; p < 4; ++p)
                        acc[p][o] += wv * v[p + kx + 1];
                }
            }
        }
    }

    double dacc = 0.0;
    #pragma unroll
    for (int p = 0; p < 4; ++p) {
        float ss = 0.f;
        #pragma unroll
        for (int o = 0; o < 8; ++o) {
            float d = acc[p][o] + PD_EPS;
            ss += d*d;
        }
        dacc += (double)sqrtf(ss);
    }

    #pragma unroll
    for (int off2 = 32; off2 > 0; off2 >>= 1)
        dacc += __shfl_down(dacc, off2, 64);
    int wid = tid >> 6, lane = tid & 63;
    if (lane == 0) sred[wid] = dacc;
    __syncthreads();
    if (tid == 0) {
        double ssum = 0.0;
        for (int w = 0; w < 7; ++w) ssum += sred[w];
        scores[pair*NSTR + strip] = ssum;
    }
}

// ---------------------------------------------------------------- sampling
__global__ void sample_kernel(char* __restrict__ ws)
{
    __shared__ double cum[BB][NP];
    const double* scores = (const double*)(ws + WS_SCORES);
    int* idxs = (int*)(ws + WS_IDX);
    int tid = threadIdx.x;                // 128
    if (tid < BB) {
        double tot = 0.0;
        for (int t = 0; t < NP; ++t) {
            const double* sp = scores + (tid*NP + t)*NSTR;
            double s = 0.0;
            for (int u = 0; u < NSTR; ++u) s += sp[u];
            tot += sqrt(s);
        }
        double run = 0.0;
        for (int t = 0; t < NP; ++t) {
            const double* sp = scores + (tid*NP + t)*NSTR;
            double s = 0.0;
            for (int u = 0; u < NSTR; ++u) s += sp[u];
            run += sqrt(s) / tot;
            cum[tid][t] = run;
        }
    }
    __syncthreads();
    {
        int b = tid / MM, m = tid % MM;
        double target = (double)((float)m / 15.f);
        int best = 0;
        double bv = fabs(cum[b][0] - target);
        for (int t = 1; t < NP; ++t) {
            double v = fabs(cum[b][t] - target);
            if (v < bv) { bv = v; best = t; }   // strict: first min wins
        }
        idxs[tid] = best;
    }
}

// ---------------------------------------------------------------- resblock conv
// block = one selected frame x one strip; same single-stage structure and
// one-ky-ahead preload. combined 7x7 3->3; y -> d_out + BN partials.
__global__ __launch_bounds__(NTH) void resconv_kernel(
    const float* __restrict__ x, char* __restrict__ ws, float* __restrict__ out)
{
    __shared__ __align__(16) float tile[CIN][TROWS][TCOLS];
    __shared__ double sred[7][6];

    const float* wc    = (const float*)(ws + WS_WC);
    const float* bias2 = (const float*)(ws + WS_BIAS2);
    const float* zp    = (const float*)(ws + WS_ZERO);
    const int* idxs    = (const int*)(ws + WS_IDX);
    float* part        = (float*)(ws + WS_PART);

    int B = blockIdx.x;                        // 896 blocks, 896%8==0
    int work = (B & 7) * 112 + (B >> 3);
    int n = work / NSTR, strip = work - n*NSTR;
    int b = n / MM;
    int l = idxs[n];
    const float* src = x + (size_t)(b*LL + l) * (CIN*HW);
    float* ybase = out + (size_t)n * (COUT*HW);
    int x0col = strip*16 - 4;

    int tid = threadIdx.x;
    int r  = tid >> 2;
    int cg = tid & 3;

    float* tf = &tile[0][0][0];
    #pragma unroll
    for (int k = 0; k < 5; ++k) {
        CHUNK_ADDR;
        const float* pa = vld ? (src + off) : zp;
        float4 va = *(const float4*)pa;
        if (idx < NCHUNK) *(float4*)&tf[li] = va;
    }
    __syncthreads();

    float acc[4][3];
    #pragma unroll
    for (int p = 0; p < 4; ++p) { acc[p][0]=0.f; acc[p][1]=0.f; acc[p][2]=0.f; }

    #pragma unroll 1
    for (int c = 0; c < CIN; ++c) {
        const float* tc = &tile[c][r][cg*4];
        float4 n0 = *(const float4*)&tc[0];
        float4 n1 = *(const float4*)&tc[4];
        float4 n2 = *(const float4*)&tc[8];
        #pragma unroll
        for (int ky = 0; ky < 7; ++ky) {
            float v[12];
            *(float4*)&v[0] = n0;
            *(float4*)&v[4] = n1;
            *(float4*)&v[8] = n2;
            if (ky < 6) {
                const float* tn = tc + (ky + 1)*TCOLS;
                n0 = *(const float4*)&tn[0];
                n1 = *(const float4*)&tn[4];
                n2 = *(const float4*)&tn[8];
            }
            const float* wrow = wc + (c*7 + ky)*28;   // uniform -> s_load
            #pragma unroll
            for (int kx = 0; kx < 7; ++kx) {
                #pragma unroll
                for (int o = 0; o < 3; ++o) {
                    float wv = wrow[kx*4 + o];        // SGPR operand
                    #pragma unroll
                    for (int p = 0; p < 4; ++p)
                        acc[p][o] += wv * v[p + kx + 1];
                }
            }
        }
    }

    double sm0=0, sm1=0, sm2=0, sq0=0, sq1=0, sq2=0;
    float bb0 = bias2[0], bb1 = bias2[1], bb2 = bias2[2];
    int ocol = strip*16 + cg*4;
    float4 yv; float* pyv = (float*)&yv;
    #pragma unroll
    for (int p = 0; p < 4; ++p) {
        float val = acc[p][0] + bb0;
        pyv[p] = val; sm0 += val; sq0 += (double)val*val;
    }
    *(float4*)&ybase[0*HW + r*WW + ocol] = yv;
    #pragma unroll
    for (int p = 0; p < 4; ++p) {
        float val = acc[p][1] + bb1;
        pyv[p] = val; sm1 += val; sq1 += (double)val*val;
    }
    *(float4*)&ybase[1*HW + r*WW + ocol] = yv;
    #pragma unroll
    for (int p = 0; p < 4; ++p) {
        float val = acc[p][2] + bb2;
        pyv[p] = val; sm2 += val; sq2 += (double)val*val;
    }
    *(float4*)&ybase[2*HW + r*WW + ocol] = yv;

    double vals[6] = {sm0, sm1, sm2, sq0, sq1, sq2};
    #pragma unroll
    for (int j = 0; j < 6; ++j) {
        #pragma unroll
        for (int off2 = 32; off2 > 0; off2 >>= 1)
            vals[j] += __shfl_down(vals[j], off2, 64);
    }
    int wid = tid >> 6, lane = tid & 63;
    if (lane == 0) {
        #pragma unroll
        for (int j = 0; j < 6; ++j) sred[wid][j] = vals[j];
    }
    __syncthreads();
    if (tid < 6) {
        double s = 0.0;
        for (int w = 0; w < 7; ++w) s += sred[w][tid];
        part[B*6 + tid] = (float)s;
    }
}

// ---------------------------------------------------------------- stats reduce
__global__ void statreduce_kernel(char* __restrict__ ws)
{
    const float* part = (const float*)(ws + WS_PART);
    float* stats = (float*)(ws + WS_STATS);
    int tid = threadIdx.x;            // 384: 6 cols x 64 lanes
    int j = tid >> 6, lane = tid & 63;
    double s = 0.0;
    for (int n = lane; n < 896; n += 64) s += (double)part[n*6 + j];
    #pragma unroll
    for (int off = 32; off > 0; off >>= 1)
        s += __shfl_down(s, off, 64);
    if (lane == 0) stats[j] = (float)s;
}

// ---------------------------------------------------------------- finalize
__global__ __launch_bounds__(256) void finalize_kernel(
    const float* __restrict__ x, const float* __restrict__ gamma,
    const float* __restrict__ beta, const char* __restrict__ ws,
    float* __restrict__ out)
{
    const float* stats = (const float*)(ws + WS_STATS);
    const int* idxs    = (const int*)(ws + WS_IDX);
    int i4 = blockIdx.x * 256 + threadIdx.x;
    int i  = i4 * 4;
    int n  = i / (COUT*HW);
    int c  = (i / HW) % COUT;
    int hw = i % HW;
    int b  = n / MM;
    int l  = idxs[n];
    const float Ninv = 1.f / (float)(BB*MM*HW);
    float mean  = stats[c] * Ninv;
    float var   = stats[3+c] * Ninv - mean*mean;
    float scale = gamma[c] / sqrtf(var + BN_EPS);
    float shift = beta[c] - mean*scale;
    float4 y  = *(const float4*)&out[i];
    float4 xv = *(const float4*)&x[((size_t)(b*LL + l)*CIN + c)*HW + hw];
    float4 r;
    r.x = xv.x + fmaxf(y.x*scale + shift, 0.f);
    r.y = xv.y + fmaxf(y.y*scale + shift, 0.f);
    r.z = xv.z + fmaxf(y.z*scale + shift, 0.f);
    r.w = xv.w + fmaxf(y.w*scale + shift, 0.f);
    *(float4*)&out[i] = r;
}

// ---------------------------------------------------------------- launch
extern "C" void kernel_launch(void* const* d_in, const int* in_sizes, int n_in,
                              void* d_out, int out_size, void* d_ws, size_t ws_size,
                              hipStream_t stream)
{
    const float* x       = (const float*)d_in[0];
    const float* conv_w  = (const float*)d_in[1];
    const float* conv_b  = (const float*)d_in[2];
    const float* bneck_w = (const float*)d_in[3];
    const float* gamma   = (const float*)d_in[4];
    const float* beta    = (const float*)d_in[5];
    float* out = (float*)d_out;
    char* ws   = (char*)d_ws;

    prep_kernel<<<1, 256, 0, stream>>>(conv_w, conv_b, bneck_w, ws);
    score_kernel<<<BB*NP*NSTR, NTH, 0, stream>>>(x, ws);
    sample_kernel<<<1, 128, 0, stream>>>(ws);
    resconv_kernel<<<BB*MM*NSTR, NTH, 0, stream>>>(x, ws, out);
    statreduce_kernel<<<1, 384, 0, stream>>>(ws);
    int total4 = (BB*MM*COUT*HW) / 4;
    finalize_kernel<<<total4 / 256, 256, 0, stream>>>(x, gamma, beta, ws, out);
}